// Round 10
// baseline (119.812 us; speedup 1.0000x reference)
//
#include <hip/hip_runtime.h>
#include <hip/hip_bf16.h>

#define EMB 768
#define HEADS 12
#define DKV 64
#define BATCH 2
#define SEQ 2048
#define NTOK (BATCH*SEQ)   // 4096

typedef float f32x4 __attribute__((ext_vector_type(4)));
typedef float f32x16 __attribute__((ext_vector_type(16)));
typedef unsigned short u16;
typedef u16 u16x8 __attribute__((ext_vector_type(8)));
typedef u16 u16x4 __attribute__((ext_vector_type(4)));
typedef __bf16 bf16x8 __attribute__((ext_vector_type(8)));

__device__ __forceinline__ u16 f2bf(float f) {
  return __builtin_bit_cast(u16, (__bf16)f);
}
__device__ __forceinline__ float fexp2(float x) {
#if __has_builtin(__builtin_amdgcn_exp2f)
  return __builtin_amdgcn_exp2f(x);
#else
  return exp2f(x);
#endif
}
__device__ __forceinline__ f32x4 mfma16(u16x8 a, u16x8 b, f32x4 c) {
  return __builtin_amdgcn_mfma_f32_16x16x32_bf16(
      __builtin_bit_cast(bf16x8, a), __builtin_bit_cast(bf16x8, b), c, 0, 0, 0);
}
__device__ __forceinline__ f32x16 mfma32(u16x8 a, u16x8 b, f32x16 c) {
  return __builtin_amdgcn_mfma_f32_32x32x16_bf16(
      __builtin_bit_cast(bf16x8, a), __builtin_bit_cast(bf16x8, b), c, 0, 0, 0);
}
// async global->LDS, 16B/lane; LDS dest must be wave-uniform base + lane*16
__device__ __forceinline__ void gload16(const void* g, void* l) {
  __builtin_amdgcn_global_load_lds(
      (const __attribute__((address_space(1))) void*)g,
      (__attribute__((address_space(3))) void*)l, 16, 0, 0);
}

// ---------------- fused cast pass: 3 x's + 4 W's fp32 -> bf16 ----------------
__global__ void cast_all_k(
    const float* __restrict__ x0, const float* __restrict__ x1, const float* __restrict__ x2,
    const float* __restrict__ w0, const float* __restrict__ w1,
    const float* __restrict__ w2, const float* __restrict__ w3,
    u16* __restrict__ X0, u16* __restrict__ X1, u16* __restrict__ X2,
    u16* __restrict__ W0, u16* __restrict__ W1, u16* __restrict__ W2, u16* __restrict__ W3,
    float wscale0)
{
  const int NX = NTOK*EMB/8;   // 393216
  const int NW = EMB*EMB/8;    // 73728
  const int total = 3*NX + 4*NW;
  int i = blockIdx.x*256 + threadIdx.x;
  for (; i < total; i += gridDim.x*256) {
    const float* s; u16* d; int off; float sc = 1.f;
    if (i < 3*NX) {
      int which = i / NX; off = i - which*NX;
      s = which==0 ? x0 : which==1 ? x1 : x2;
      d = which==0 ? X0 : which==1 ? X1 : X2;
    } else {
      int j = i - 3*NX; int which = j / NW; off = j - which*NW;
      s = which==0 ? w0 : which==1 ? w1 : which==2 ? w2 : w3;
      d = which==0 ? W0 : which==1 ? W1 : which==2 ? W2 : W3;
      if (which == 0) sc = wscale0;
    }
    float4 a = reinterpret_cast<const float4*>(s)[off*2];
    float4 b = reinterpret_cast<const float4*>(s)[off*2+1];
    u16x8 o;
    o[0]=f2bf(a.x*sc); o[1]=f2bf(a.y*sc); o[2]=f2bf(a.z*sc); o[3]=f2bf(a.w*sc);
    o[4]=f2bf(b.x*sc); o[5]=f2bf(b.y*sc); o[6]=f2bf(b.z*sc); o[7]=f2bf(b.w*sc);
    reinterpret_cast<u16x8*>(d)[off] = o;
  }
}

// ---------------- GEMM core, m97 structure (unchanged from round 9) ----------------
template<int MODE>
__device__ __forceinline__ void gemm_core(
    const u16* __restrict__ A, const u16* __restrict__ Bm,
    const float* __restrict__ bias, float bscale, void* __restrict__ outp,
    u16* __restrict__ At, u16* __restrict__ Bt, int m0, int n0)
{
  const int t = threadIdx.x;
  const int w = t >> 6, lane = t & 63, lg = lane >> 4, lr = lane & 15;
  const int wr = w >> 1, wc = w & 1;

  f32x4 acc[4][4] = {};

  const int crow = (w*4)*8 + (lane >> 3);
  const int csl  = lane & 7;

  auto STAGE = [&](int kb) {
    #pragma unroll
    for (int i = 0; i < 4; ++i) {
      int row = crow + i*8;
      int sg = csl ^ (row & 7);
      gload16(A  + (size_t)(m0+row)*EMB + kb + sg*8, &At[(w*4+i)*512]);
      gload16(Bm + (size_t)(n0+row)*EMB + kb + sg*8, &Bt[(w*4+i)*512]);
    }
  };

  auto COMPUTE = [&]() {
    u16x8 af[4][2], bf[4][2];
    #pragma unroll
    for (int fm = 0; fm < 4; ++fm)
      #pragma unroll
      for (int kk = 0; kk < 2; ++kk) {
        int r = wr*64 + fm*16 + lr;
        int p = (lg + 4*kk) ^ (r & 7);
        af[fm][kk] = *reinterpret_cast<const u16x8*>(&At[r*64 + p*8]);
      }
    #pragma unroll
    for (int fn = 0; fn < 4; ++fn)
      #pragma unroll
      for (int kk = 0; kk < 2; ++kk) {
        int r = wc*64 + fn*16 + lr;
        int p = (lg + 4*kk) ^ (r & 7);
        bf[fn][kk] = *reinterpret_cast<const u16x8*>(&Bt[r*64 + p*8]);
      }
    __builtin_amdgcn_s_setprio(1);
    #pragma unroll
    for (int fm = 0; fm < 4; ++fm)
      #pragma unroll
      for (int fn = 0; fn < 4; ++fn)
        #pragma unroll
        for (int kk = 0; kk < 2; ++kk)
          acc[fm][fn] = mfma16(af[fm][kk], bf[fn][kk], acc[fm][fn]);
    __builtin_amdgcn_s_setprio(0);
  };

  const int NSTEP = EMB/64;   // 12
  #pragma unroll
  for (int ts = 0; ts < NSTEP; ++ts) {
    STAGE(ts*64);
    __syncthreads();
    COMPUTE();
    if (ts+1 < NSTEP) __syncthreads();
  }

  #pragma unroll
  for (int fm = 0; fm < 4; ++fm)
    #pragma unroll
    for (int fn = 0; fn < 4; ++fn) {
      const int mb = m0 + wr*64 + fm*16 + lg*4;
      const int e  = n0 + wc*64 + fn*16 + lr;
      if constexpr (MODE == 2) {
        int bb = mb >> 11, sb = mb & 2047, h = e >> 6, d = e & 63;
        u16x4 o4;
        #pragma unroll
        for (int j = 0; j < 4; ++j) o4[j] = f2bf(acc[fm][fn][j] + bias[e]*bscale);
        *reinterpret_cast<u16x4*>(
            reinterpret_cast<u16*>(outp) + (((size_t)(bb*HEADS+h))*DKV + d)*SEQ + sb) = o4;
      } else {
        #pragma unroll
        for (int j = 0; j < 4; ++j) {
          int m = mb + j;
          float val = acc[fm][fn][j] + bias[e]*bscale;
          if constexpr (MODE == 0) {
            int bb = m >> 11, s = m & 2047, h = e >> 6, d = e & 63;
            reinterpret_cast<u16*>(outp)[(((size_t)(bb*HEADS+h))*SEQ + s)*DKV + d] = f2bf(val);
          } else {
            reinterpret_cast<float*>(outp)[(size_t)m*EMB + e] = val;
          }
        }
      }
    }
}

__global__ __launch_bounds__(256) void qkv_k(
    const u16* __restrict__ Xq, const u16* __restrict__ Xk, const u16* __restrict__ Xv,
    const u16* __restrict__ Wq, const u16* __restrict__ Wk, const u16* __restrict__ Wv,
    const float* __restrict__ bq, const float* __restrict__ bk, const float* __restrict__ bv,
    u16* __restrict__ Qh, u16* __restrict__ Kh, u16* __restrict__ Vh, float csc)
{
  __shared__ __align__(16) u16 At[128*64];
  __shared__ __align__(16) u16 Bt[128*64];
  const int m0 = blockIdx.x*128, n0 = blockIdx.y*128;
  const int z = blockIdx.z;
  if (z == 0)
    gemm_core<0>(Xq, Wq, bq, csc, Qh, At, Bt, m0, n0);
  else if (z == 1)
    gemm_core<0>(Xk, Wk, bk, 1.f, Kh, At, Bt, m0, n0);
  else
    gemm_core<2>(Xv, Wv, bv, 1.f, Vh, At, Bt, m0, n0);
}

__global__ __launch_bounds__(256) void gemm_out_k(
    const u16* __restrict__ A, const u16* __restrict__ Bm,
    const float* __restrict__ bias, float* __restrict__ outp)
{
  __shared__ __align__(16) u16 At[128*64];
  __shared__ __align__(16) u16 Bt[128*64];
  gemm_core<1>(A, Bm, bias, 1.f, outp, At, Bt, blockIdx.x*128, blockIdx.y*128);
}

// ---------------- flash attention: 32x32x16 MFMA, zero-shuffle PV ----------------
// 4 waves = 2 q-groups (qg=w>>1, 32 q each) x 2 key-halves (kh=w&1, 32 keys of each
// 64-key tile). S = mfma32(K, Q): C col=lane&31=q, row=key crow(r,hi)=(r&3)+8*(r>>2)
// +4hi [m74/m101]. Per-lane softmax (16 scores), defer-max THR=8, partial lrun.
// PV: O^T = mfma32(V^T, PA). V^T stored in LDS with key-permutation sigma:
// key=8m+c+4hi_k -> pos=16*(m>>1)+8*hi_k+4*(m&1)+c, so the B-fragment lane->k map
// lands on each lane's OWN p values: PA[ks][j] = p[8ks+j]. P never touches LDS.
// K staged via global_load_lds (pre-swizzled source); V reg-staged (sigma+XOR).
// 1 barrier/tile, dbuf, 2x-unrolled literal buffer index. Cross-kh merge per block.
__global__ __launch_bounds__(256) void flash_attn_k(
    const u16* __restrict__ Q, const u16* __restrict__ K, const u16* __restrict__ VT,
    u16* __restrict__ av)
{
  __shared__ __align__(16) u16 Kt[2][64*64];   // [key][d], phys16 = (d/8)^(key&7)
  __shared__ __align__(16) u16 Vt[2][64*64];   // [d][sigma(key)], phys16 ^= (d&7)

  const int t = threadIdx.x;
  const int w = t >> 6, lane = t & 63;
  const int hi = lane >> 5, q32 = lane & 31;
  const int qg = w >> 1, kh = w & 1;
  const int qb = blockIdx.x, bh = blockIdx.y;
  const u16* Qb = Q  + (size_t)bh*SEQ*DKV;
  const u16* Kb = K  + (size_t)bh*SEQ*DKV;
  const u16* Vb = VT + (size_t)bh*DKV*SEQ;

  const int qrow = qb*64 + qg*32 + q32;
  u16x8 qf[4];
  #pragma unroll
  for (int ks = 0; ks < 4; ++ks)
    qf[ks] = *reinterpret_cast<const u16x8*>(Qb + (size_t)qrow*DKV + ks*16 + hi*8);

  f32x16 acc[2] = {};            // partial O^T over this wave's key half
  float mrun = -1e30f, lrun = 0.f;

  u16x8 vr[2];
  auto STAGE_K = [&](int kt0, int bi) {
    #pragma unroll
    for (int c = 0; c < 2; ++c) {
      int ls = t + c*256;                 // linear 16B chunk 0..511
      int row = ls >> 3, sl = ls & 7;
      int sg = sl ^ (row & 7);            // pre-swizzled global slot
      gload16(Kb + (size_t)(kt0+row)*DKV + sg*8, &Kt[bi][ls*8]);
    }
  };
  auto LOAD_V = [&](int kt0) {
    #pragma unroll
    for (int c = 0; c < 2; ++c) {
      int gc = t + c*256;
      int row = gc >> 3, a = gc & 7;      // row=d, global 16B chunk a (keys 8a..8a+7)
      vr[c] = *reinterpret_cast<const u16x8*>(Vb + (size_t)row*SEQ + kt0 + a*8);
    }
  };

  const int NT = SEQ/64;   // 32

#define WRITE_V(bi)                                                           \
  do {                                                                        \
    _Pragma("unroll")                                                         \
    for (int c = 0; c < 2; ++c) {                                             \
      int gc = t + c*256;                                                     \
      int row = gc >> 3, a = gc & 7;                                          \
      int p0 = (2*(a>>1))   ^ (row & 7);                                      \
      int p1 = (2*(a>>1)+1) ^ (row & 7);                                      \
      int sub = (a & 1)*4;                                                    \
      u16x4 lo4 = { vr[c][0], vr[c][1], vr[c][2], vr[c][3] };                 \
      u16x4 hi4 = { vr[c][4], vr[c][5], vr[c][6], vr[c][7] };                 \
      *reinterpret_cast<u16x4*>(&Vt[bi][row*64 + p0*8 + sub]) = lo4;          \
      *reinterpret_cast<u16x4*>(&Vt[bi][row*64 + p1*8 + sub]) = hi4;          \
    }                                                                         \
  } while (0)

#define TILE(bi, kt)                                                          \
  do {                                                                        \
    if ((kt)+1 < NT) { STAGE_K(((kt)+1)*64, (bi)^1); LOAD_V(((kt)+1)*64); }   \
    f32x16 s = {};                                                            \
    {                                                                         \
      const int key = kh*32 + q32;                                            \
      const int kbase = key*64;                                               \
      __builtin_amdgcn_s_setprio(1);                                          \
      _Pragma("unroll")                                                       \
      for (int ks = 0; ks < 4; ++ks) {                                        \
        int ph = (2*ks + hi) ^ (key & 7);                                     \
        u16x8 kf = *reinterpret_cast<const u16x8*>(&Kt[bi][kbase + ph*8]);    \
        s = mfma32(kf, qf[ks], s);                                            \
      }                                                                       \
      __builtin_amdgcn_s_setprio(0);                                          \
    }                                                                         \
    float m0_ = fmaxf(fmaxf(s[0],s[1]), fmaxf(s[2],s[3]));                    \
    float m1_ = fmaxf(fmaxf(s[4],s[5]), fmaxf(s[6],s[7]));                    \
    float m2_ = fmaxf(fmaxf(s[8],s[9]), fmaxf(s[10],s[11]));                  \
    float m3_ = fmaxf(fmaxf(s[12],s[13]), fmaxf(s[14],s[15]));                \
    float pmax = fmaxf(fmaxf(m0_, m1_), fmaxf(m2_, m3_));                     \
    if (__any(pmax > mrun + 8.f)) {                                           \
      float pm = fmaxf(pmax, __shfl_xor(pmax, 32));                           \
      float mnew = fmaxf(mrun, pm);                                           \
      float corr = fexp2(mrun - mnew);                                        \
      mrun = mnew; lrun *= corr;                                              \
      acc[0] = acc[0] * corr;                                                 \
      acc[1] = acc[1] * corr;                                                 \
    }                                                                         \
    float p_[16];                                                             \
    _Pragma("unroll")                                                         \
    for (int r = 0; r < 16; ++r) p_[r] = fexp2(s[r] - mrun);                  \
    lrun += ((p_[0]+p_[1])+(p_[2]+p_[3])) + ((p_[4]+p_[5])+(p_[6]+p_[7]))     \
          + ((p_[8]+p_[9])+(p_[10]+p_[11])) + ((p_[12]+p_[13])+(p_[14]+p_[15])); \
    u16x8 pa0, pa1;                                                           \
    _Pragma("unroll")                                                         \
    for (int j = 0; j < 8; ++j) { pa0[j] = f2bf(p_[j]); pa1[j] = f2bf(p_[8+j]); } \
    {                                                                         \
      __builtin_amdgcn_s_setprio(1);                                          \
      _Pragma("unroll")                                                       \
      for (int ks = 0; ks < 2; ++ks) {                                        \
        int ksg = kh*2 + ks;                                                  \
        u16x8 pav = ks ? pa1 : pa0;                                           \
        int ph = (2*ksg + hi) ^ (q32 & 7);                                    \
        u16x8 v0 = *reinterpret_cast<const u16x8*>(&Vt[bi][q32*64 + ph*8]);   \
        acc[0] = mfma32(v0, pav, acc[0]);                                     \
        u16x8 v1 = *reinterpret_cast<const u16x8*>(&Vt[bi][(32+q32)*64 + ph*8]); \
        acc[1] = mfma32(v1, pav, acc[1]);                                     \
      }                                                                       \
      __builtin_amdgcn_s_setprio(0);                                          \
    }                                                                         \
    if ((kt)+1 < NT) WRITE_V((bi)^1);                                         \
    __syncthreads();                                                          \
  } while (0)

  STAGE_K(0, 0); LOAD_V(0);
  WRITE_V(0);
  __syncthreads();

  for (int kt = 0; kt < NT; kt += 2) {
    TILE(0, kt);
    TILE(1, kt+1);
  }
#undef TILE
#undef WRITE_V

  // ---- merge the two key-halves (kh=0 <- kh=1) ----
  lrun += __shfl_xor(lrun, 32);                 // full l over this wave's 32 keys
  float* sc = reinterpret_cast<float*>(&Kt[0][0]);     // [qg][lane][32] f32, swizzled
  float2* ml = reinterpret_cast<float2*>(&Vt[0][0]);   // [qg][lane]

  if (kh == 1) {
    #pragma unroll
    for (int db = 0; db < 2; ++db)
      #pragma unroll
      for (int g4 = 0; g4 < 4; ++g4) {
        int ph = (db*4 + g4) ^ (lane & 7);
        f32x4 v = { acc[db][g4*4+0], acc[db][g4*4+1], acc[db][g4*4+2], acc[db][g4*4+3] };
        *reinterpret_cast<f32x4*>(&sc[qg*2048 + lane*32 + ph*4]) = v;
      }
    float2 m2; m2.x = mrun; m2.y = lrun;
    ml[qg*64 + lane] = m2;
  }
  __syncthreads();
  if (kh == 0) {
    float2 mo = ml[qg*64 + lane];
    float g  = fmaxf(mrun, mo.x);
    float wsf = fexp2(mrun - g), wof = fexp2(mo.x - g);
    float inv = 1.0f / (lrun*wsf + mo.y*wof);
    wsf *= inv; wof *= inv;
    const int b = bh / HEADS, h = bh % HEADS;
    u16* op = av + ((size_t)(b*SEQ + qrow))*EMB + h*64;
    #pragma unroll
    for (int db = 0; db < 2; ++db)
      #pragma unroll
      for (int rg = 0; rg < 4; ++rg) {
        int ph = (db*4 + rg) ^ (lane & 7);
        f32x4 o = *reinterpret_cast<const f32x4*>(&sc[qg*2048 + lane*32 + ph*4]);
        u16x4 o4;
        #pragma unroll
        for (int c = 0; c < 4; ++c)
          o4[c] = f2bf(acc[db][rg*4+c]*wsf + o[c]*wof);
        *reinterpret_cast<u16x4*>(op + db*32 + rg*8 + hi*4) = o4;
      }
  }
}

// ---------------- launcher: 4 kernels ----------------
extern "C" void kernel_launch(void* const* d_in, const int* in_sizes, int n_in,
                              void* d_out, int out_size, void* d_ws, size_t ws_size,
                              hipStream_t stream) {
  const float* xq_f = (const float*)d_in[0];
  const float* xk_f = (const float*)d_in[1];
  const float* xv_f = (const float*)d_in[2];
  const float* Wq = (const float*)d_in[3];
  const float* bq = (const float*)d_in[4];
  const float* Wk = (const float*)d_in[5];
  const float* bk = (const float*)d_in[6];
  const float* Wv = (const float*)d_in[7];
  const float* bv = (const float*)d_in[8];
  const float* Wo = (const float*)d_in[9];
  const float* bo = (const float*)d_in[10];

  const size_t NX = (size_t)NTOK*EMB;
  const size_t NW = (size_t)EMB*EMB;
  u16* Xc0 = (u16*)d_ws;
  u16* Xc1 = Xc0 + NX;
  u16* Xc2 = Xc1 + NX;
  u16* Wc0 = Xc2 + NX;
  u16* Wc1 = Wc0 + NW;
  u16* Wc2 = Wc1 + NW;
  u16* Wc3 = Wc2 + NW;
  u16* Qh  = Wc3 + NW;
  u16* Kh  = Qh + NX;
  u16* Vh  = Kh + NX;        // [B][H][DKV][SEQ] (V^T)
  u16* Xb  = Xc0;            // attn out aliases Xc (dead after qkv)

  const float csc = 0.125f * 1.4426950408889634f;

  cast_all_k<<<dim3(2048), dim3(256), 0, stream>>>(
      xq_f, xk_f, xv_f, Wq, Wk, Wv, Wo,
      Xc0, Xc1, Xc2, Wc0, Wc1, Wc2, Wc3, csc);

  qkv_k<<<dim3(NTOK/128, EMB/128, 3), dim3(256), 0, stream>>>(
      Xc0, Xc1, Xc2, Wc0, Wc1, Wc2, bq, bk, bv, Qh, Kh, Vh, csc);

  flash_attn_k<<<dim3(SEQ/64, BATCH*HEADS), dim3(256), 0, stream>>>(Qh, Kh, Vh, Xb);

  gemm_out_k<<<dim3(NTOK/128, EMB/128), dim3(256), 0, stream>>>(Xb, Wc3, bo, (float*)d_out);
}